// Round 1
// baseline (410.099 us; speedup 1.0000x reference)
//
#include <hip/hip_runtime.h>
#include <hip/hip_bf16.h>

// CrossViewAttention: B=4, V=6, C=256, H=W=64 (HW=4096), heads=8, dh=32.
//
// Pipeline (all on `stream`, per-b K/V buffer reuse is safe via stream order):
//   1. convert_weights: Wq/Wk/Wv/Wo fp32 -> bf16
//   2. transpose_mean:  x[b][v][c][w] fp32 -> xt[b][v][w][c] bf16, xbar[b][w][c] bf16 (mean over v)
//   3. gemm (fp32 out): Qloc[b][o][w] = Wq @ xbar
//   4. per b: gemm K, gemm V (bf16 out), attention -> attnT[b][w][c] bf16
//   5. gemm (fp32 out): d_out[b][o][w] = Wo @ attnT

typedef __bf16 bf16x8 __attribute__((ext_vector_type(8)));
typedef float f32x4 __attribute__((ext_vector_type(4)));

#define HW 4096
#define C_DIM 256
#define NV 6
#define NB 4

__global__ __launch_bounds__(256) void convert_weights_kernel(
    const float* __restrict__ Wq, const float* __restrict__ Wk,
    const float* __restrict__ Wv, const float* __restrict__ Wo,
    __hip_bfloat16* __restrict__ out)
{
    const float* srcs[4] = {Wq, Wk, Wv, Wo};
    const int m = blockIdx.y;
    const int i = blockIdx.x * 256 + threadIdx.x;
    out[m * 65536 + i] = __float2bfloat16(srcs[m][i]);
}

// 64x64 tile transpose via LDS; accumulates per-view sum for xbar.
__global__ __launch_bounds__(256) void transpose_mean_kernel(
    const float* __restrict__ x,        // [B][V][C][HW]
    __hip_bfloat16* __restrict__ xt,    // [B][V][HW][C]
    __hip_bfloat16* __restrict__ xbar)  // [B][HW][C]
{
    __shared__ float tile[64][65];      // +1 pad: conflict-free both phases
    const int w0 = blockIdx.x * 64;
    const int c0 = blockIdx.y * 64;
    const int b  = blockIdx.z;
    const int t  = threadIdx.x;
    const int li = t & 63;              // lane within 64
    const int qi = t >> 6;              // quarter 0..3
    float acc[16];
#pragma unroll
    for (int i = 0; i < 16; ++i) acc[i] = 0.f;

    for (int v = 0; v < NV; ++v) {
        const float* src = x + (((size_t)b * NV + v) * C_DIM + c0) * HW + w0;
#pragma unroll
        for (int i = 0; i < 16; ++i) {
            const int c = qi + 4 * i;
            tile[li][c] = src[(size_t)c * HW + li];   // coalesced read along w
        }
        __syncthreads();
        __hip_bfloat16* dst = xt + (((size_t)b * NV + v) * HW + w0) * C_DIM + c0;
#pragma unroll
        for (int i = 0; i < 16; ++i) {
            const int w = qi + 4 * i;
            const float val = tile[w][li];
            acc[i] += val;
            dst[(size_t)w * C_DIM + li] = __float2bfloat16(val);  // coalesced along c
        }
        __syncthreads();
    }
    __hip_bfloat16* dbar = xbar + ((size_t)b * HW + w0) * C_DIM + c0;
#pragma unroll
    for (int i = 0; i < 16; ++i) {
        const int w = qi + 4 * i;
        dbar[(size_t)w * C_DIM + li] = __float2bfloat16(acc[i] * (1.f / 6.f));
    }
}

// C[z][256][4096] = A[256][256] @ B^T(z)[4096][256]^T   (B given row-major [n][k])
// 128x128 block tile, 4 waves of 64x64, BK=32, 16x16x32 bf16 MFMA.
// LDS layout per tile: [kb 0..3][row 0..127][8 bf16] -> conflict-free ds_read_b128,
// staged with global_load_lds width=16 (linear dest, per-lane global src).
template<int OUT_BF16>
__global__ __launch_bounds__(256) void gemm_kernel(
    const __hip_bfloat16* __restrict__ A,    // [256][256] weights
    const __hip_bfloat16* __restrict__ Bt,   // [z][4096][256]
    void* __restrict__ Cv,                   // [z][256][4096]
    size_t strideB, size_t strideC)
{
    __shared__ __align__(16) __hip_bfloat16 Alds[4096];  // 8 KB
    __shared__ __align__(16) __hip_bfloat16 Blds[4096];  // 8 KB
    const int n0 = blockIdx.x * 128;
    const int m0 = blockIdx.y * 128;
    const int z  = blockIdx.z;
    const __hip_bfloat16* B = Bt + (size_t)z * strideB;

    const int t  = threadIdx.x;
    const int wv = t >> 6, l = t & 63;
    const int wr = wv >> 1, wc = wv & 1;    // wave's 64x64 quadrant

    f32x4 acc[4][4];
#pragma unroll
    for (int i = 0; i < 4; ++i)
#pragma unroll
        for (int j = 0; j < 4; ++j) {
            acc[i][j][0] = 0.f; acc[i][j][1] = 0.f;
            acc[i][j][2] = 0.f; acc[i][j][3] = 0.f;
        }

    // waves 0,1 stage A; waves 2,3 stage B (4 calls each, 1 KB per call)
    const int matB = wv >> 1;
    const __hip_bfloat16* gsrc = matB ? B : A;
    __hip_bfloat16* lbase = matB ? Blds : Alds;
    const int rbase = matB ? n0 : m0;

    const int kb_l = l >> 4;
    const int rl   = l & 15;

    for (int k0 = 0; k0 < 256; k0 += 32) {
#pragma unroll
        for (int c2 = 0; c2 < 4; ++c2) {
            const int c    = (wv & 1) * 4 + c2;
            const int kb   = c >> 1, half = c & 1;
            const int row  = half * 64 + l;
            const __hip_bfloat16* g = gsrc + (size_t)(rbase + row) * 256 + (k0 + kb * 8);
            __builtin_amdgcn_global_load_lds(
                (const __attribute__((address_space(1))) void*)g,
                (__attribute__((address_space(3))) void*)(lbase + kb * 1024 + half * 512),
                16, 0, 0);
        }
        __syncthreads();   // compiler drains vmcnt(0) before s_barrier

        bf16x8 af[4], bfr[4];
#pragma unroll
        for (int i = 0; i < 4; ++i)
            af[i] = *(const bf16x8*)&Alds[kb_l * 1024 + (wr * 64 + i * 16 + rl) * 8];
#pragma unroll
        for (int j = 0; j < 4; ++j)
            bfr[j] = *(const bf16x8*)&Blds[kb_l * 1024 + (wc * 64 + j * 16 + rl) * 8];
#pragma unroll
        for (int i = 0; i < 4; ++i)
#pragma unroll
            for (int j = 0; j < 4; ++j)
                acc[i][j] = __builtin_amdgcn_mfma_f32_16x16x32_bf16(af[i], bfr[j], acc[i][j], 0, 0, 0);
        __syncthreads();
    }

    // C/D layout: col = lane&15, row = (lane>>4)*4 + reg
    const int r0 = (l >> 4) * 4;
    const int cl = l & 15;
#pragma unroll
    for (int i = 0; i < 4; ++i) {
        const int row = m0 + wr * 64 + i * 16 + r0;
#pragma unroll
        for (int j = 0; j < 4; ++j) {
            const int col = n0 + wc * 64 + j * 16 + cl;
            if (OUT_BF16) {
                __hip_bfloat16* Cp = (__hip_bfloat16*)Cv + (size_t)z * strideC;
#pragma unroll
                for (int r = 0; r < 4; ++r)
                    Cp[(size_t)(row + r) * HW + col] = __float2bfloat16(acc[i][j][r]);
            } else {
                float* Cp = (float*)Cv + (size_t)z * strideC;
#pragma unroll
                for (int r = 0; r < 4; ++r)
                    Cp[(size_t)(row + r) * HW + col] = acc[i][j][r];
            }
        }
    }
}

// One thread per (pixel w, head h): softmax over V=6 views, 32-dim head.
__global__ __launch_bounds__(256) void attn_kernel(
    const float* __restrict__ Qloc,       // [256][4096] (this b)
    const __hip_bfloat16* __restrict__ K, // [6][256][4096]
    const __hip_bfloat16* __restrict__ V, // [6][256][4096]
    __hip_bfloat16* __restrict__ outT)    // [4096][256] (this b)
{
    const int w = blockIdx.x * 256 + threadIdx.x;
    const int h = blockIdx.y;
    const float scale = 0.17677669529663687f;  // 32^-0.5

    float q[32];
    const float* Qp = Qloc + (size_t)(h * 32) * HW + w;
#pragma unroll
    for (int d = 0; d < 32; ++d) q[d] = Qp[(size_t)d * HW];

    float s[NV];
#pragma unroll
    for (int v = 0; v < NV; ++v) {
        const __hip_bfloat16* Kp = K + ((size_t)v * C_DIM + h * 32) * HW + w;
        float a = 0.f;
#pragma unroll
        for (int d = 0; d < 32; ++d) a += q[d] * __bfloat162float(Kp[(size_t)d * HW]);
        s[v] = a * scale;
    }
    float m = s[0];
#pragma unroll
    for (int v = 1; v < NV; ++v) m = fmaxf(m, s[v]);
    float den = 0.f;
#pragma unroll
    for (int v = 0; v < NV; ++v) { s[v] = __expf(s[v] - m); den += s[v]; }
    const float inv = 1.f / den;

    float o[32];
#pragma unroll
    for (int d = 0; d < 32; ++d) o[d] = 0.f;
#pragma unroll
    for (int v = 0; v < NV; ++v) {
        const float p = s[v] * inv;
        const __hip_bfloat16* Vp = V + ((size_t)v * C_DIM + h * 32) * HW + w;
#pragma unroll
        for (int d = 0; d < 32; ++d) o[d] += p * __bfloat162float(Vp[(size_t)d * HW]);
    }
    __hip_bfloat16* op = outT + (size_t)w * C_DIM + h * 32;
#pragma unroll
    for (int d = 0; d < 32; ++d) op[d] = __float2bfloat16(o[d]);
}

extern "C" void kernel_launch(void* const* d_in, const int* in_sizes, int n_in,
                              void* d_out, int out_size, void* d_ws, size_t ws_size,
                              hipStream_t stream)
{
    const float* x  = (const float*)d_in[0];
    const float* Wq = (const float*)d_in[1];
    const float* Wk = (const float*)d_in[2];
    const float* Wv = (const float*)d_in[3];
    const float* Wo = (const float*)d_in[4];

    char* ws = (char*)d_ws;
    const size_t MB = 1024ull * 1024ull;
    __hip_bfloat16* Wbf   = (__hip_bfloat16*)(ws);              // 512 KB: [4][256][256]
    __hip_bfloat16* xt    = (__hip_bfloat16*)(ws + 1 * MB);     // 48 MB: [4][6][4096][256]
    __hip_bfloat16* xbar  = (__hip_bfloat16*)(ws + 49 * MB);    // 8 MB:  [4][4096][256]
    float*          Qloc  = (float*)         (ws + 57 * MB);    // 16 MB: [4][256][4096]
    __hip_bfloat16* Kbuf  = (__hip_bfloat16*)(ws + 73 * MB);    // 12 MB: [6][256][4096] (per-b reuse)
    __hip_bfloat16* Vbuf  = (__hip_bfloat16*)(ws + 85 * MB);    // 12 MB
    __hip_bfloat16* attnT = (__hip_bfloat16*)(ws + 97 * MB);    // 8 MB:  [4][4096][256]
    (void)ws_size; (void)in_sizes; (void)n_in; (void)out_size;

    const __hip_bfloat16* WqB = Wbf;
    const __hip_bfloat16* WkB = Wbf + 65536;
    const __hip_bfloat16* WvB = Wbf + 131072;
    const __hip_bfloat16* WoB = Wbf + 196608;

    const size_t SL = (size_t)HW * C_DIM;  // 1048576 elements per slice

    convert_weights_kernel<<<dim3(256, 4), 256, 0, stream>>>(Wq, Wk, Wv, Wo, Wbf);
    transpose_mean_kernel<<<dim3(HW / 64, C_DIM / 64, NB), 256, 0, stream>>>(x, xt, xbar);

    // Qloc = Wq @ xbar  (fp32 out), z = b
    gemm_kernel<0><<<dim3(32, 2, NB), 256, 0, stream>>>(WqB, xbar, Qloc, SL, SL);

    for (int b = 0; b < NB; ++b) {
        const __hip_bfloat16* xtb = xt + (size_t)b * NV * SL;
        gemm_kernel<1><<<dim3(32, 2, NV), 256, 0, stream>>>(WkB, xtb, Kbuf, SL, SL);
        gemm_kernel<1><<<dim3(32, 2, NV), 256, 0, stream>>>(WvB, xtb, Vbuf, SL, SL);
        attn_kernel<<<dim3(HW / 256, 8), 256, 0, stream>>>(
            Qloc + (size_t)b * SL, Kbuf, Vbuf, attnT + (size_t)b * SL);
    }

    // out = Wo @ attnT  (fp32 out), z = b
    gemm_kernel<0><<<dim3(32, 2, NB), 256, 0, stream>>>(WoB, attnT, (float*)d_out, SL, SL);
}

// Round 2
// 162.815 us; speedup vs baseline: 2.5188x; 2.5188x over previous
//
#include <hip/hip_runtime.h>
#include <hip/hip_bf16.h>

// CrossViewAttention: B=4, V=6, C=256, H=W=64 (HW=4096), heads=8, dh=32.
//
// Pipeline:
//   1. convert_weights: Wq/Wk/Wv/Wo fp32 -> bf16
//   2. transpose_mean:  x[b][v][c][w] -> xt[b][v][w][c] bf16, xbar[b][w][c] bf16 (mean over v)
//   3. gemm: Qloc[b][w][c] fp32 = xbar @ Wq^T     ([w][c] layout!)
//   4. gemm: Kt[b][v][w][c]   = xt @ Wk^T, Vt = xt @ Wv^T  (bf16, [w][c] layout)
//   5. attn: one thread per (b,w,h) — contiguous 64B loads per head
//   6. gemm: d_out[b][o][w] fp32 = Wo @ attnT

typedef __bf16 bf16x8 __attribute__((ext_vector_type(8)));
typedef float f32x4 __attribute__((ext_vector_type(4)));

#define HW 4096
#define C_DIM 256
#define NV 6
#define NB 4

__global__ __launch_bounds__(256) void convert_weights_kernel(
    const float* __restrict__ Wq, const float* __restrict__ Wk,
    const float* __restrict__ Wv, const float* __restrict__ Wo,
    __hip_bfloat16* __restrict__ out)
{
    const float* srcs[4] = {Wq, Wk, Wv, Wo};
    const int m = blockIdx.y;
    const int i = blockIdx.x * 256 + threadIdx.x;
    out[m * 65536 + i] = __float2bfloat16(srcs[m][i]);
}

// 64x64 tile transpose via LDS; accumulates per-view sum for xbar.
__global__ __launch_bounds__(256) void transpose_mean_kernel(
    const float* __restrict__ x,        // [B][V][C][HW]
    __hip_bfloat16* __restrict__ xt,    // [B][V][HW][C]
    __hip_bfloat16* __restrict__ xbar)  // [B][HW][C]
{
    __shared__ float tile[64][65];
    const int w0 = blockIdx.x * 64;
    const int c0 = blockIdx.y * 64;
    const int b  = blockIdx.z;
    const int t  = threadIdx.x;
    const int li = t & 63;
    const int qi = t >> 6;
    float acc[16];
#pragma unroll
    for (int i = 0; i < 16; ++i) acc[i] = 0.f;

    for (int v = 0; v < NV; ++v) {
        const float* src = x + (((size_t)b * NV + v) * C_DIM + c0) * HW + w0;
#pragma unroll
        for (int i = 0; i < 16; ++i) {
            const int c = qi + 4 * i;
            tile[li][c] = src[(size_t)c * HW + li];
        }
        __syncthreads();
        __hip_bfloat16* dst = xt + (((size_t)b * NV + v) * HW + w0) * C_DIM + c0;
#pragma unroll
        for (int i = 0; i < 16; ++i) {
            const int w = qi + 4 * i;
            const float val = tile[w][li];
            acc[i] += val;
            dst[(size_t)w * C_DIM + li] = __float2bfloat16(val);
        }
        __syncthreads();
    }
    __hip_bfloat16* dbar = xbar + ((size_t)b * HW + w0) * C_DIM + c0;
#pragma unroll
    for (int i = 0; i < 16; ++i) {
        const int w = qi + 4 * i;
        dbar[(size_t)w * C_DIM + li] = __float2bfloat16(acc[i] * (1.f / 6.f));
    }
}

// Generic 128x128-tile GEMM, K=256:  C[z][row][col] = A_z[row][k] * B_z[col][k]
// A rows: M-dim (grid.y*128), B rows: N-dim (grid.x*128); both k-contiguous, k-stride 256.
// C row-major with leading dim ldc. 4 waves of 64x64, BK=32, mfma 16x16x32 bf16.
template<int OUT_BF16>
__global__ __launch_bounds__(256) void gemm_generic(
    const __hip_bfloat16* __restrict__ Abase, size_t strideA,
    const __hip_bfloat16* __restrict__ Bbase, size_t strideB,
    void* __restrict__ Cv, size_t strideC, int ldc)
{
    __shared__ __align__(16) __hip_bfloat16 Alds[4096];  // 8 KB: [kb 0..3][row 0..127][8]
    __shared__ __align__(16) __hip_bfloat16 Blds[4096];
    const int n0 = blockIdx.x * 128;
    const int m0 = blockIdx.y * 128;
    const int z  = blockIdx.z;
    const __hip_bfloat16* A = Abase + (size_t)z * strideA;
    const __hip_bfloat16* B = Bbase + (size_t)z * strideB;

    const int t  = threadIdx.x;
    const int wv = t >> 6, l = t & 63;
    const int wr = wv >> 1, wc = wv & 1;

    f32x4 acc[4][4];
#pragma unroll
    for (int i = 0; i < 4; ++i)
#pragma unroll
        for (int j = 0; j < 4; ++j) {
            acc[i][j][0] = 0.f; acc[i][j][1] = 0.f;
            acc[i][j][2] = 0.f; acc[i][j][3] = 0.f;
        }

    const int matB = wv >> 1;
    const __hip_bfloat16* gsrc = matB ? B : A;
    __hip_bfloat16* lbase = matB ? Blds : Alds;
    const int rbase = matB ? n0 : m0;

    const int kb_l = l >> 4;
    const int rl   = l & 15;

    for (int k0 = 0; k0 < 256; k0 += 32) {
#pragma unroll
        for (int c2 = 0; c2 < 4; ++c2) {
            const int c    = (wv & 1) * 4 + c2;
            const int kb   = c >> 1, half = c & 1;
            const int row  = half * 64 + l;
            const __hip_bfloat16* g = gsrc + (size_t)(rbase + row) * 256 + (k0 + kb * 8);
            __builtin_amdgcn_global_load_lds(
                (const __attribute__((address_space(1))) void*)g,
                (__attribute__((address_space(3))) void*)(lbase + kb * 1024 + half * 512),
                16, 0, 0);
        }
        __syncthreads();

        bf16x8 af[4], bfr[4];
#pragma unroll
        for (int i = 0; i < 4; ++i)
            af[i] = *(const bf16x8*)&Alds[kb_l * 1024 + (wr * 64 + i * 16 + rl) * 8];
#pragma unroll
        for (int j = 0; j < 4; ++j)
            bfr[j] = *(const bf16x8*)&Blds[kb_l * 1024 + (wc * 64 + j * 16 + rl) * 8];
#pragma unroll
        for (int i = 0; i < 4; ++i)
#pragma unroll
            for (int j = 0; j < 4; ++j)
                acc[i][j] = __builtin_amdgcn_mfma_f32_16x16x32_bf16(af[i], bfr[j], acc[i][j], 0, 0, 0);
        __syncthreads();
    }

    // C/D layout: col = lane&15, row = (lane>>4)*4 + reg
    const int r0 = (l >> 4) * 4;
    const int cl = l & 15;
#pragma unroll
    for (int i = 0; i < 4; ++i) {
        const int row = m0 + wr * 64 + i * 16 + r0;
#pragma unroll
        for (int j = 0; j < 4; ++j) {
            const int col = n0 + wc * 64 + j * 16 + cl;
            if (OUT_BF16) {
                __hip_bfloat16* Cp = (__hip_bfloat16*)Cv + (size_t)z * strideC;
#pragma unroll
                for (int r = 0; r < 4; ++r)
                    Cp[(size_t)(row + r) * ldc + col] = __float2bfloat16(acc[i][j][r]);
            } else {
                float* Cp = (float*)Cv + (size_t)z * strideC;
#pragma unroll
                for (int r = 0; r < 4; ++r)
                    Cp[(size_t)(row + r) * ldc + col] = acc[i][j][r];
            }
        }
    }
}

// One thread per (b, w, h): all loads contiguous 64B per head slice.
__global__ __launch_bounds__(256) void attn_kernel(
    const float* __restrict__ Qloc,        // [nb][4096][256]
    const __hip_bfloat16* __restrict__ Kt, // [nb*6][4096][256]
    const __hip_bfloat16* __restrict__ Vt,
    __hip_bfloat16* __restrict__ outT)     // [nb][4096][256]
{
    const int t  = blockIdx.x * 256 + threadIdx.x;
    const int h  = t & 7;
    const int bw = t >> 3;                 // b*4096 + w
    const int b  = bw >> 12;
    const int w  = bw & 4095;
    const float scale = 0.17677669529663687f;  // 32^-0.5

    float q[32];
    const f32x4* Qp = (const f32x4*)(Qloc + (size_t)bw * C_DIM + h * 32);
#pragma unroll
    for (int i = 0; i < 8; ++i) {
        f32x4 v4 = Qp[i];
        q[4 * i] = v4[0]; q[4 * i + 1] = v4[1]; q[4 * i + 2] = v4[2]; q[4 * i + 3] = v4[3];
    }

    float s[NV];
#pragma unroll
    for (int v = 0; v < NV; ++v) {
        const bf16x8* Kp = (const bf16x8*)(Kt + ((size_t)(b * NV + v) * HW + w) * C_DIM + h * 32);
        float a = 0.f;
#pragma unroll
        for (int i = 0; i < 4; ++i) {
            bf16x8 kv = Kp[i];
#pragma unroll
            for (int j = 0; j < 8; ++j) a += q[8 * i + j] * (float)kv[j];
        }
        s[v] = a * scale;
    }
    float m = s[0];
#pragma unroll
    for (int v = 1; v < NV; ++v) m = fmaxf(m, s[v]);
    float den = 0.f;
#pragma unroll
    for (int v = 0; v < NV; ++v) { s[v] = __expf(s[v] - m); den += s[v]; }
    const float inv = 1.f / den;

    float o[32];
#pragma unroll
    for (int d = 0; d < 32; ++d) o[d] = 0.f;
#pragma unroll
    for (int v = 0; v < NV; ++v) {
        const float p = s[v] * inv;
        const bf16x8* Vp = (const bf16x8*)(Vt + ((size_t)(b * NV + v) * HW + w) * C_DIM + h * 32);
#pragma unroll
        for (int i = 0; i < 4; ++i) {
            bf16x8 vv = Vp[i];
#pragma unroll
            for (int j = 0; j < 8; ++j) o[8 * i + j] += p * (float)vv[j];
        }
    }
    __hip_bfloat16* op = outT + (size_t)bw * C_DIM + h * 32;
#pragma unroll
    for (int i = 0; i < 4; ++i) {
        bf16x8 ov;
#pragma unroll
        for (int j = 0; j < 8; ++j) ov[j] = (__bf16)o[8 * i + j];
        *(bf16x8*)(op + 8 * i) = ov;
    }
}

extern "C" void kernel_launch(void* const* d_in, const int* in_sizes, int n_in,
                              void* d_out, int out_size, void* d_ws, size_t ws_size,
                              hipStream_t stream)
{
    const float* x  = (const float*)d_in[0];
    const float* Wq = (const float*)d_in[1];
    const float* Wk = (const float*)d_in[2];
    const float* Wv = (const float*)d_in[3];
    const float* Wo = (const float*)d_in[4];
    (void)in_sizes; (void)n_in; (void)out_size;

    char* ws = (char*)d_ws;
    const size_t MB = 1024ull * 1024ull;
    const size_t SL = (size_t)HW * C_DIM;                    // 1M elements per slice

    __hip_bfloat16* Wbf   = (__hip_bfloat16*)(ws);           // 512 KB
    __hip_bfloat16* xt    = (__hip_bfloat16*)(ws + 1 * MB);  // 48 MB [4*6][4096][256]
    float*          Qloc  = (float*)         (ws + 49 * MB); // 16 MB [4][4096][256] fp32
    __hip_bfloat16* xbar  = (__hip_bfloat16*)(ws + 65 * MB); // 8 MB  [4][4096][256]
    __hip_bfloat16* attnT = xbar;                            // overlay: xbar dead after Qloc gemm
    __hip_bfloat16* Kt    = (__hip_bfloat16*)(ws + 73 * MB);

    const bool big = ws_size >= 169 * MB;
    __hip_bfloat16* Vt = big ? (__hip_bfloat16*)(ws + 121 * MB)
                             : (__hip_bfloat16*)(ws + 85 * MB);

    const __hip_bfloat16* WqB = Wbf;
    const __hip_bfloat16* WkB = Wbf + 65536;
    const __hip_bfloat16* WvB = Wbf + 131072;
    const __hip_bfloat16* WoB = Wbf + 196608;

    convert_weights_kernel<<<dim3(256, 4), 256, 0, stream>>>(Wq, Wk, Wv, Wo, Wbf);
    transpose_mean_kernel<<<dim3(HW / 64, C_DIM / 64, NB), 256, 0, stream>>>(x, xt, xbar);

    // Qloc[b][w][c] fp32 = xbar @ Wq^T
    gemm_generic<0><<<dim3(2, 32, NB), 256, 0, stream>>>(xbar, SL, WqB, 0, Qloc, SL, 256);

    if (big) {
        gemm_generic<1><<<dim3(2, 32, NB * NV), 256, 0, stream>>>(xt, SL, WkB, 0, Kt, SL, 256);
        gemm_generic<1><<<dim3(2, 32, NB * NV), 256, 0, stream>>>(xt, SL, WvB, 0, Vt, SL, 256);
        attn_kernel<<<dim3(NB * 128), 256, 0, stream>>>(Qloc, Kt, Vt, attnT);
    } else {
        for (int b = 0; b < NB; ++b) {
            const __hip_bfloat16* xtb = xt + (size_t)b * NV * SL;
            gemm_generic<1><<<dim3(2, 32, NV), 256, 0, stream>>>(xtb, SL, WkB, 0, Kt, SL, 256);
            gemm_generic<1><<<dim3(2, 32, NV), 256, 0, stream>>>(xtb, SL, WvB, 0, Vt, SL, 256);
            attn_kernel<<<dim3(128), 256, 0, stream>>>(
                Qloc + (size_t)b * SL, Kt, Vt, attnT + (size_t)b * SL);
        }
    }

    // d_out[b][o][w] fp32 = Wo @ attnT
    gemm_generic<0><<<dim3(32, 2, NB), 256, 0, stream>>>(WoB, 0, attnT, SL, (float*)d_out, SL, 4096);
}